// Round 4
// baseline (642.106 us; speedup 1.0000x reference)
//
#include <hip/hip_runtime.h>

// Shapes fixed by setup_inputs(): b=8, s=4096, h=16, p=64, n=64, L=64.
// Reduction: out[b,h,p,n] = sum_t exp(Total(b,h) - P(b,h,t)) * X[b,t,h,p] * B[b,t,h,n]
// where P = inclusive prefix-sum of A over t, Total = P[s-1]. (Chunked scan telescopes.)

constexpr int Bn = 8;
constexpr int S  = 4096;
constexpr int H  = 16;
constexpr int P  = 64;
constexpr int N  = 64;

constexpr int NCH = 8;         // t-chunks per (b,h) pair -> 1024 blocks = 4/CU exactly
constexpr int TCH = S / NCH;   // 512 timesteps per chunk
constexpr int TB  = 32;        // timesteps staged per LDS buffer
constexpr int NIT = TCH / TB;  // 16 buffer iterations per block

typedef unsigned int u32;

// async global->LDS, 16B per lane. LDS dest is wave-uniform base + lane*16.
__device__ __forceinline__ void gll16(const float* g, void* l) {
  __builtin_amdgcn_global_load_lds(
      (const __attribute__((address_space(1))) u32*)g,
      (__attribute__((address_space(3))) u32*)l, 16, 0, 0);
}
__device__ __forceinline__ void gll4(const float* g, void* l) {
  __builtin_amdgcn_global_load_lds(
      (const __attribute__((address_space(1))) u32*)g,
      (__attribute__((address_space(3))) u32*)l, 4, 0, 0);
}

// ---------------- Kernel 1: per-(b,h) prefix scan of A -> weights ----------------
__global__ __launch_bounds__(256) void scan_weights(
    const float* __restrict__ A, float* __restrict__ W) {
  const int pair = blockIdx.x;         // 0..Bn*H-1
  const int bb = pair / H, hh = pair % H;
  const int tid = threadIdx.x;
  constexpr int TPT = S / 256;         // 16 elements per thread

  float vals[TPT];
  float local = 0.f;
  const int t0 = tid * TPT;
  #pragma unroll
  for (int i = 0; i < TPT; ++i) {
    float a = A[((size_t)bb * S + t0 + i) * H + hh];
    local += a;
    vals[i] = local;                   // inclusive within thread
  }

  __shared__ float sums[256];
  sums[tid] = local;
  __syncthreads();
  for (int off = 1; off < 256; off <<= 1) {
    float v = sums[tid];
    float add = (tid >= off) ? sums[tid - off] : 0.f;
    __syncthreads();
    sums[tid] = v + add;
    __syncthreads();
  }
  const float total = sums[255];
  const float excl  = sums[tid] - local;

  float* Wp = W + (size_t)pair * S;
  #pragma unroll
  for (int i = 0; i < TPT; ++i) {
    Wp[t0 + i] = __expf(total - (excl + vals[i]));  // exponent <= 0 (A <= 0)
  }
}

// ---------------- Kernel 2: weighted outer-product accumulation ----------------
// One block per (pair, chunk). 256 threads = 4 waves. Each lane owns an 8x8 tile
// of the 64x64 output; the 4 waves split the staged timesteps (wave w -> rows
// w*8..w*8+7 of each 32-row buffer) and combine partials via an LDS tree.
// Staging is pure global_load_lds (no VGPR round-trip).
//
// NO LAMBDAS in this kernel. Rounds 1-3 evidence: any hot state captured by
// reference in a lambda gets memory-homed at the IR level (address taken,
// alloca never re-promoted) -> acc[8][8] lived in scratch (VGPR=64 reported,
// +1.1 GB HBM scratch traffic, VALUBusy 9%). Staging is a macro; the
// reduction tree is written inline with static indices only.
#define STAGE(buf, tt0)                                                   \
  do {                                                                    \
    float4* Xs_ = &smem[buf][0];                                          \
    float4* Bs_ = &smem[buf][512];                                        \
    float*  Ws_ = (float*)&smem[buf][1024];                               \
    const float* px_ = gx + (size_t)(tt0) * HP;                           \
    const float* pb_ = gb + (size_t)(tt0) * HN;                           \
    gll16(px_,          Xs_ + wid * 128);      /* X rows w*8 .. +3 */     \
    gll16(px_ + 4 * HP, Xs_ + wid * 128 + 64); /* X rows w*8+4 .. +7 */   \
    gll16(pb_,          Bs_ + wid * 128);                                 \
    gll16(pb_ + 4 * HN, Bs_ + wid * 128 + 64);                            \
    if (wid == 0) gll4(gw + (tt0), Ws_);       /* 32 decay weights */     \
  } while (0)

__global__ __launch_bounds__(256)
__attribute__((amdgpu_waves_per_eu(4, 4)))
void outer_accum(
    const float* __restrict__ X, const float* __restrict__ Bm,
    const float* __restrict__ W, float* __restrict__ out) {
  // buffer layout (float4 units): [0..511]=X rows [32][16], [512..1023]=B rows,
  // [1024..1039]=W (64 floats, first 32 valid). Double-buffered: 33,280 B.
  __shared__ float4 smem[2][1040];

  const int bid  = blockIdx.x;
  const int pair = bid / NCH;
  const int ch   = bid % NCH;
  const int tid  = threadIdx.x;
  const int lane = tid & 63;
  const int wid  = tid >> 6;           // wave id 0..3
  const int t_begin = ch * TCH;

  // compute mapping: lane covers an 8x8 tile of the 64x64 (p,n) output
  const int pr = (lane >> 3) * 8;      // p base
  const int nc = (lane & 7) * 8;       // n base

  const int bb = pair / H, hh = pair % H;
  constexpr int HP = H * P;            // 1024 floats: X row stride over t
  constexpr int HN = H * N;            // 1024 floats: B row stride over t

  // staging: wave w fills buffer rows w*8 .. w*8+7 (two 64-float4 issues of 4 rows)
  const int r0 = wid * 8 + (lane >> 4);      // staged row for issue 0 (issue 1: +4)
  const int c0 = (lane & 15) * 4;            // float column
  const float* gx = X  + (size_t)bb * S * HP + (size_t)hh * P + (size_t)r0 * HP + c0;
  const float* gb = Bm + (size_t)bb * S * HN + (size_t)hh * N + (size_t)r0 * HN + c0;
  const float* gw = W + (size_t)pair * S + (lane & 31);  // lanes 32..63: harmless dups

  float acc[8][8];
  #pragma unroll
  for (int i = 0; i < 8; ++i)
    #pragma unroll
    for (int k = 0; k < 8; ++k) acc[i][k] = 0.f;

  STAGE(0, t_begin);
  __syncthreads();                               // drains vmcnt -> buf0 ready

  for (int it = 0; it < NIT; ++it) {
    const int cur = it & 1;
    if (it + 1 < NIT) STAGE(cur ^ 1, t_begin + (it + 1) * TB);  // async prefetch

    const float* Xs = (const float*)&smem[cur][0];
    const float* Bs = (const float*)&smem[cur][512];
    const float* Ws = (const float*)&smem[cur][1024];
    #pragma unroll
    for (int j = 0; j < 8; ++j) {
      const int tt = wid * 8 + j;                // this wave's timestep in buffer
      const float w = Ws[tt];                    // broadcast read
      const float4 xa = *(const float4*)(Xs + tt * 64 + pr);
      const float4 xb = *(const float4*)(Xs + tt * 64 + pr + 4);
      const float4 ba = *(const float4*)(Bs + tt * 64 + nc);
      const float4 bc = *(const float4*)(Bs + tt * 64 + nc + 4);
      const float xs0 = xa.x * w, xs1 = xa.y * w, xs2 = xa.z * w, xs3 = xa.w * w;
      const float xs4 = xb.x * w, xs5 = xb.y * w, xs6 = xb.z * w, xs7 = xb.w * w;
      const float bs0 = ba.x, bs1 = ba.y, bs2 = ba.z, bs3 = ba.w;
      const float bs4 = bc.x, bs5 = bc.y, bs6 = bc.z, bs7 = bc.w;
      #pragma unroll
      for (int i = 0; i < 8; ++i) {
        const float xi = (i == 0) ? xs0 : (i == 1) ? xs1 : (i == 2) ? xs2 :
                         (i == 3) ? xs3 : (i == 4) ? xs4 : (i == 5) ? xs5 :
                         (i == 6) ? xs6 : xs7;
        acc[i][0] = fmaf(xi, bs0, acc[i][0]);
        acc[i][1] = fmaf(xi, bs1, acc[i][1]);
        acc[i][2] = fmaf(xi, bs2, acc[i][2]);
        acc[i][3] = fmaf(xi, bs3, acc[i][3]);
        acc[i][4] = fmaf(xi, bs4, acc[i][4]);
        acc[i][5] = fmaf(xi, bs5, acc[i][5]);
        acc[i][6] = fmaf(xi, bs6, acc[i][6]);
        acc[i][7] = fmaf(xi, bs7, acc[i][7]);
      }
    }
    __syncthreads();   // drains prefetch; also guards buffer reuse
  }

  // ---- cross-wave reduction of the 4 t-phase partials (inline LDS tree) ----
  // red: 2 regions of 64*64 floats carved from the (contiguous) smem array.
  float* red = (float*)&smem[0][0];
  const int rbase = ((pr * 64 + nc) >> 2);       // float4 index of this lane's tile

  // step 1: waves 1,3 publish to regions 0,1
  if (wid == 1 || wid == 3) {
    float4* r = (float4*)(red + (wid >> 1) * 4096) + rbase;
    #pragma unroll
    for (int i = 0; i < 8; ++i) {
      r[i * 16]     = make_float4(acc[i][0], acc[i][1], acc[i][2], acc[i][3]);
      r[i * 16 + 1] = make_float4(acc[i][4], acc[i][5], acc[i][6], acc[i][7]);
    }
  }
  __syncthreads();
  // step 2: waves 0,2 absorb regions 0,1
  if (wid == 0 || wid == 2) {
    const float4* r = (const float4*)(red + (wid >> 1) * 4096) + rbase;
    #pragma unroll
    for (int i = 0; i < 8; ++i) {
      const float4 v0 = r[i * 16];
      const float4 v1 = r[i * 16 + 1];
      acc[i][0] += v0.x; acc[i][1] += v0.y; acc[i][2] += v0.z; acc[i][3] += v0.w;
      acc[i][4] += v1.x; acc[i][5] += v1.y; acc[i][6] += v1.z; acc[i][7] += v1.w;
    }
  }
  __syncthreads();
  // step 3: wave 2 publishes its sum to region 0
  if (wid == 2) {
    float4* r = (float4*)red + rbase;
    #pragma unroll
    for (int i = 0; i < 8; ++i) {
      r[i * 16]     = make_float4(acc[i][0], acc[i][1], acc[i][2], acc[i][3]);
      r[i * 16 + 1] = make_float4(acc[i][4], acc[i][5], acc[i][6], acc[i][7]);
    }
  }
  __syncthreads();
  // step 4: wave 0 absorbs and combines the NCH disjoint t-chunks via atomics
  if (wid == 0) {
    const float4* r = (const float4*)red + rbase;
    float* outp = out + (size_t)pair * P * N;    // out[b,h,p,n]
    #pragma unroll
    for (int i = 0; i < 8; ++i) {
      const float4 v0 = r[i * 16];
      const float4 v1 = r[i * 16 + 1];
      atomicAdd(&outp[(size_t)(pr + i) * N + nc + 0], acc[i][0] + v0.x);
      atomicAdd(&outp[(size_t)(pr + i) * N + nc + 1], acc[i][1] + v0.y);
      atomicAdd(&outp[(size_t)(pr + i) * N + nc + 2], acc[i][2] + v0.z);
      atomicAdd(&outp[(size_t)(pr + i) * N + nc + 3], acc[i][3] + v0.w);
      atomicAdd(&outp[(size_t)(pr + i) * N + nc + 4], acc[i][4] + v1.x);
      atomicAdd(&outp[(size_t)(pr + i) * N + nc + 5], acc[i][5] + v1.y);
      atomicAdd(&outp[(size_t)(pr + i) * N + nc + 6], acc[i][6] + v1.z);
      atomicAdd(&outp[(size_t)(pr + i) * N + nc + 7], acc[i][7] + v1.w);
    }
  }
}

extern "C" void kernel_launch(void* const* d_in, const int* in_sizes, int n_in,
                              void* d_out, int out_size, void* d_ws, size_t ws_size,
                              hipStream_t stream) {
  const float* X = (const float*)d_in[0];   // (b, s, h, p)
  const float* A = (const float*)d_in[1];   // (b, s, h)
  const float* B = (const float*)d_in[2];   // (b, s, h, n)
  float* out = (float*)d_out;               // (b, h, p, n)
  float* W   = (float*)d_ws;                // Bn*H*S floats = 2 MB scratch

  // out is poisoned 0xAA before every launch; atomics need zeros
  hipMemsetAsync(d_out, 0, (size_t)out_size * sizeof(float), stream);

  scan_weights<<<Bn * H, 256, 0, stream>>>(A, W);
  outer_accum<<<Bn * H * NCH, 256, 0, stream>>>(X, B, W, out);
}

// Round 5
// 318.963 us; speedup vs baseline: 2.0131x; 2.0131x over previous
//
#include <hip/hip_runtime.h>

// Shapes fixed by setup_inputs(): b=8, s=4096, h=16, p=64, n=64, L=64.
// Reduction: out[b,h,p,n] = sum_t exp(Total(b,h) - P(b,h,t)) * X[b,t,h,p] * B[b,t,h,n]
// where P = inclusive prefix-sum of A over t, Total = P[s-1]. (Chunked scan telescopes.)

constexpr int Bn = 8;
constexpr int S  = 4096;
constexpr int H  = 16;
constexpr int P  = 64;
constexpr int N  = 64;

constexpr int NCH = 8;         // t-chunks per (b,h) pair -> 1024 blocks = 4/CU exactly
constexpr int TCH = S / NCH;   // 512 timesteps per chunk
constexpr int TB  = 32;        // timesteps staged per LDS buffer
constexpr int NIT = TCH / TB;  // 16 buffer iterations per block

typedef unsigned int u32;

// async global->LDS, 16B per lane. LDS dest is wave-uniform base + lane*16.
__device__ __forceinline__ void gll16(const float* g, void* l) {
  __builtin_amdgcn_global_load_lds(
      (const __attribute__((address_space(1))) u32*)g,
      (__attribute__((address_space(3))) u32*)l, 16, 0, 0);
}
__device__ __forceinline__ void gll4(const float* g, void* l) {
  __builtin_amdgcn_global_load_lds(
      (const __attribute__((address_space(1))) u32*)g,
      (__attribute__((address_space(3))) u32*)l, 4, 0, 0);
}

// ---------------- Kernel 1: per-(b,h) prefix scan of A -> weights ----------------
__global__ __launch_bounds__(256) void scan_weights(
    const float* __restrict__ A, float* __restrict__ W) {
  const int pair = blockIdx.x;         // 0..Bn*H-1
  const int bb = pair / H, hh = pair % H;
  const int tid = threadIdx.x;
  constexpr int TPT = S / 256;         // 16 elements per thread

  float vals[TPT];
  float local = 0.f;
  const int t0 = tid * TPT;
  #pragma unroll
  for (int i = 0; i < TPT; ++i) {
    float a = A[((size_t)bb * S + t0 + i) * H + hh];
    local += a;
    vals[i] = local;                   // inclusive within thread
  }

  __shared__ float sums[256];
  sums[tid] = local;
  __syncthreads();
  for (int off = 1; off < 256; off <<= 1) {
    float v = sums[tid];
    float add = (tid >= off) ? sums[tid - off] : 0.f;
    __syncthreads();
    sums[tid] = v + add;
    __syncthreads();
  }
  const float total = sums[255];
  const float excl  = sums[tid] - local;

  float* Wp = W + (size_t)pair * S;
  #pragma unroll
  for (int i = 0; i < TPT; ++i) {
    Wp[t0 + i] = __expf(total - (excl + vals[i]));  // exponent <= 0 (A <= 0)
  }
}

// ---------------- Kernel 2: weighted outer-product accumulation ----------------
// One block per (pair, chunk). 256 threads = 4 waves = 2 wave-pairs.
// Each 128-lane wave-pair covers the FULL 64x64 output with 8x4 per-lane tiles;
// the two pairs split the staged timesteps (pair 0: tt 0..15, pair 1: tt 16..31).
// Cross-pair combine is one 16 KB LDS publish/absorb; t-chunks combine via atomics.
//
// REGISTER BUDGET NOTE (rounds 1-4 post-mortem): this compiler pins outer_accum
// at 64 arch VGPRs regardless of __launch_bounds__ min-waves, amdgpu_waves_per_eu,
// lambda-free source, or static indexing. An 8x8 accumulator (needs ~110 regs)
// is therefore scratch-homed: VGPR=64/SGPR=112 reported identically across three
// different source structures, with +0.9-1.1 GB/dispatch HBM scratch traffic and
// VALUBusy collapsing to 9%. The 8x4 accumulator (32 regs, ~58 live total)
// mirrors round 0's proven register-resident idioms and fits the 64 budget.
#define STAGE(buf, tt0)                                                   \
  do {                                                                    \
    float4* Xs_ = &smem[buf][0];                                          \
    float4* Bs_ = &smem[buf][512];                                        \
    float*  Ws_ = (float*)&smem[buf][1024];                               \
    const float* px_ = gx + (size_t)(tt0) * HP;                           \
    const float* pb_ = gb + (size_t)(tt0) * HN;                           \
    gll16(px_,          Xs_ + wid * 128);      /* X rows w*8 .. +3 */     \
    gll16(px_ + 4 * HP, Xs_ + wid * 128 + 64); /* X rows w*8+4 .. +7 */   \
    gll16(pb_,          Bs_ + wid * 128);                                 \
    gll16(pb_ + 4 * HN, Bs_ + wid * 128 + 64);                            \
    if (wid == 0) gll4(gw + (tt0), Ws_);       /* 32 decay weights */     \
  } while (0)

__global__ __launch_bounds__(256) void outer_accum(
    const float* __restrict__ X, const float* __restrict__ Bm,
    const float* __restrict__ W, float* __restrict__ out) {
  // buffer layout (float4 units): [0..511]=X rows [32][16], [512..1023]=B rows,
  // [1024..1039]=W (64 floats, first 32 valid). Double-buffered: 33,280 B.
  __shared__ float4 smem[2][1040];

  const int bid  = blockIdx.x;
  const int pair = bid / NCH;
  const int ch   = bid % NCH;
  const int tid  = threadIdx.x;
  const int lane = tid & 63;
  const int wid  = tid >> 6;           // wave id 0..3
  const int tpair = tid >> 7;          // wave-pair id 0..1 (t-split)
  const int sub  = tid & 127;          // lane within wave-pair
  const int t_begin = ch * TCH;

  // compute mapping: lane covers an 8x4 tile of the 64x64 (p,n) output
  const int p0 = (sub >> 4) * 8;       // p base (8 groups)
  const int n0 = (sub & 15) * 4;       // n base (16 groups)

  const int bb = pair / H, hh = pair % H;
  constexpr int HP = H * P;            // 1024 floats: X row stride over t
  constexpr int HN = H * N;            // 1024 floats: B row stride over t

  // staging: wave w fills buffer rows w*8 .. w*8+7 (two 64-float4 issues of 4 rows)
  const int r0 = wid * 8 + (lane >> 4);      // staged row for issue 0 (issue 1: +4)
  const int c0 = (lane & 15) * 4;            // float column
  const float* gx = X  + (size_t)bb * S * HP + (size_t)hh * P + (size_t)r0 * HP + c0;
  const float* gb = Bm + (size_t)bb * S * HN + (size_t)hh * N + (size_t)r0 * HN + c0;
  const float* gw = W + (size_t)pair * S + (lane & 31);  // lanes 32..63: harmless dups

  float acc[8][4];
  #pragma unroll
  for (int i = 0; i < 8; ++i)
    #pragma unroll
    for (int k = 0; k < 4; ++k) acc[i][k] = 0.f;

  STAGE(0, t_begin);
  __syncthreads();                               // drains vmcnt -> buf0 ready

  for (int it = 0; it < NIT; ++it) {
    const int cur = it & 1;
    if (it + 1 < NIT) STAGE(cur ^ 1, t_begin + (it + 1) * TB);  // async prefetch

    const float* Xs = (const float*)&smem[cur][0];
    const float* Bs = (const float*)&smem[cur][512];
    const float* Ws = (const float*)&smem[cur][1024];
    #pragma unroll
    for (int j = 0; j < 16; ++j) {
      const int tt = tpair * 16 + j;             // this pair's timestep in buffer
      const float w = Ws[tt];                    // broadcast read
      const float4 xa = *(const float4*)(Xs + tt * 64 + p0);
      const float4 xb = *(const float4*)(Xs + tt * 64 + p0 + 4);
      const float4 bv = *(const float4*)(Bs + tt * 64 + n0);
      const float b0 = bv.x * w, b1 = bv.y * w, b2 = bv.z * w, b3 = bv.w * w;
      const float xv[8] = {xa.x, xa.y, xa.z, xa.w, xb.x, xb.y, xb.z, xb.w};
      #pragma unroll
      for (int i = 0; i < 8; ++i) {
        acc[i][0] = fmaf(xv[i], b0, acc[i][0]);
        acc[i][1] = fmaf(xv[i], b1, acc[i][1]);
        acc[i][2] = fmaf(xv[i], b2, acc[i][2]);
        acc[i][3] = fmaf(xv[i], b3, acc[i][3]);
      }
    }
    __syncthreads();   // drains prefetch; also guards buffer reuse
  }

  // ---- cross-pair combine: pair 1 publishes its 64x64 partial, pair 0 absorbs ----
  float* red = (float*)&smem[0][0];              // 16 KB region (fits in smem)
  const int rb = p0 * 64 + n0;                   // float index of this lane's tile

  if (tpair == 1) {
    #pragma unroll
    for (int i = 0; i < 8; ++i)
      *(float4*)(red + rb + i * 64) =
          make_float4(acc[i][0], acc[i][1], acc[i][2], acc[i][3]);
  }
  __syncthreads();
  if (tpair == 0) {
    float* outp = out + (size_t)pair * P * N;    // out[b,h,p,n]
    #pragma unroll
    for (int i = 0; i < 8; ++i) {
      const float4 v = *(const float4*)(red + rb + i * 64);
      atomicAdd(&outp[(size_t)(p0 + i) * N + n0 + 0], acc[i][0] + v.x);
      atomicAdd(&outp[(size_t)(p0 + i) * N + n0 + 1], acc[i][1] + v.y);
      atomicAdd(&outp[(size_t)(p0 + i) * N + n0 + 2], acc[i][2] + v.z);
      atomicAdd(&outp[(size_t)(p0 + i) * N + n0 + 3], acc[i][3] + v.w);
    }
  }
}

extern "C" void kernel_launch(void* const* d_in, const int* in_sizes, int n_in,
                              void* d_out, int out_size, void* d_ws, size_t ws_size,
                              hipStream_t stream) {
  const float* X = (const float*)d_in[0];   // (b, s, h, p)
  const float* A = (const float*)d_in[1];   // (b, s, h)
  const float* B = (const float*)d_in[2];   // (b, s, h, n)
  float* out = (float*)d_out;               // (b, h, p, n)
  float* W   = (float*)d_ws;                // Bn*H*S floats = 2 MB scratch

  // out is poisoned 0xAA before every launch; atomics need zeros
  hipMemsetAsync(d_out, 0, (size_t)out_size * sizeof(float), stream);

  scan_weights<<<Bn * H, 256, 0, stream>>>(A, W);
  outer_accum<<<Bn * H * NCH, 256, 0, stream>>>(X, B, W, out);
}

// Round 6
// 296.121 us; speedup vs baseline: 2.1684x; 1.0771x over previous
//
#include <hip/hip_runtime.h>

// Shapes fixed by setup_inputs(): b=8, s=4096, h=16, p=64, n=64, L=64.
// Reduction: out[b,h,p,n] = sum_t exp(Total(b,h) - P(b,h,t)) * X[b,t,h,p] * B[b,t,h,n]
// = a 64x64 GEMM with K=t=4096 per (b,h) pair -> MFMA (bf16 3-term split).

constexpr int Bn = 8;
constexpr int S  = 4096;
constexpr int H  = 16;
constexpr int P  = 64;
constexpr int N  = 64;

constexpr int NCH = 8;         // t-chunks per (b,h) pair -> 1024 blocks
constexpr int TCH = S / NCH;   // 512 timesteps per chunk
constexpr int TB  = 32;        // timesteps per K-iteration (= MFMA K)
constexpr int NIT = TCH / TB;  // 16 iterations per block

typedef __attribute__((ext_vector_type(4))) float f32x4;
typedef __attribute__((ext_vector_type(8))) short short8;

// ---------------- Kernel 1: per-(b,h) prefix scan of A -> weights ----------------
__global__ __launch_bounds__(256) void scan_weights(
    const float* __restrict__ A, float* __restrict__ W) {
  const int pair = blockIdx.x;         // 0..Bn*H-1
  const int bb = pair / H, hh = pair % H;
  const int tid = threadIdx.x;
  constexpr int TPT = S / 256;         // 16 elements per thread

  float vals[TPT];
  float local = 0.f;
  const int t0 = tid * TPT;
  #pragma unroll
  for (int i = 0; i < TPT; ++i) {
    float a = A[((size_t)bb * S + t0 + i) * H + hh];
    local += a;
    vals[i] = local;                   // inclusive within thread
  }

  __shared__ float sums[256];
  sums[tid] = local;
  __syncthreads();
  for (int off = 1; off < 256; off <<= 1) {
    float v = sums[tid];
    float add = (tid >= off) ? sums[tid - off] : 0.f;
    __syncthreads();
    sums[tid] = v + add;
    __syncthreads();
  }
  const float total = sums[255];
  const float excl  = sums[tid] - local;

  float* Wp = W + (size_t)pair * S;
  #pragma unroll
  for (int i = 0; i < TPT; ++i) {
    Wp[t0 + i] = __expf(total - (excl + vals[i]));  // exponent <= 0 (A <= 0)
  }
}

// fp32 -> (hi bf16 in low half, lo bf16 in high half), truncation split.
// x ~= bf16(hi) + bf16(lo); dropped lo*lo term ~2^-16 relative.
__device__ __forceinline__ unsigned pack_hilo(float x) {
  unsigned bx = __float_as_uint(x);
  unsigned hi = bx >> 16;
  float rf = x - __uint_as_float(bx & 0xFFFF0000u);
  unsigned lo = __float_as_uint(rf) & 0xFFFF0000u;
  return hi | lo;
}

__device__ __forceinline__ short8 mk_frag(unsigned a0, unsigned a1,
                                          unsigned a2, unsigned a3) {
  union { unsigned u[4]; short8 s; } u;
  u.u[0] = a0; u.u[1] = a1; u.u[2] = a2; u.u[3] = a3;
  return u.s;
}

// ---------------- Kernel 2: MFMA outer-product accumulation ----------------
// One block per (pair, chunk). 256 threads = 4 waves; wave w owns the 32x32
// output quadrant (m0=(w&1)*32, n0=(w>>1)*32) as 4 MFMA 16x16 tiles.
// Per iteration (32 t): transpose-stage via coalesced global dword loads
// (lane = column), pack fp32 -> (hi|lo) bf16 u32, write [p][t] LDS rows with
// stride 33 (2-way banks on both writes and frag reads - free). Fragments:
// 8x ds_read_b32 + v_perm extraction; 3 MFMA per tile per K-step
// (hi*hi + hi*lo + lo*hi). Registers stay ~90 (acc = 16 VGPR only).
__global__ __launch_bounds__(256) void outer_accum(
    const float* __restrict__ X, const float* __restrict__ Bm,
    const float* __restrict__ W, float* __restrict__ out) {
  __shared__ unsigned Xl[64 * 33];     // [p][t] hi|lo packed, stride 33 u32
  __shared__ unsigned Bl[64 * 33];     // [n][t]

  const int bid  = blockIdx.x;
  const int pair = bid / NCH;
  const int ch   = bid % NCH;
  const int tid  = threadIdx.x;
  const int lane = tid & 63;
  const int wid  = __builtin_amdgcn_readfirstlane(tid >> 6);  // 0..3, SGPR
  const int t_begin = ch * TCH;

  const int bb = pair / H, hh = pair % H;
  constexpr int HP = H * P;            // 1024 floats: X row stride over t
  constexpr int HN = H * N;            // 1024 floats: B row stride over t

  // staging: lane = column index (p for X, n for B); coalesced dword loads
  const float* gXc = X  + (size_t)bb * S * HP + (size_t)hh * P + lane;
  const float* gBc = Bm + (size_t)bb * S * HN + (size_t)hh * N + lane;
  const float* Wp  = W + (size_t)pair * S;

  // compute mapping: wave quadrant + MFMA lane roles
  const int m0 = (wid & 1) * 32;
  const int n0 = (wid >> 1) * 32;
  const int l15 = lane & 15;
  const int l4  = lane >> 4;           // k-group (k = l4*8 + j), C row-group

  f32x4 acc[2][2];
  #pragma unroll
  for (int mt = 0; mt < 2; ++mt)
    #pragma unroll
    for (int nt = 0; nt < 2; ++nt) acc[mt][nt] = (f32x4)0.f;

  for (int it = 0; it < NIT; ++it) {
    const int tb = t_begin + it * TB;
    const int tw = tb + wid * 8;       // this wave stages 8 t-rows

    // ---- load 8 X + 8 B dwords (coalesced), 8 weights ----
    float xr[8], br[8], wv[8];
    #pragma unroll
    for (int k = 0; k < 8; ++k) {
      xr[k] = gXc[(size_t)(tw + k) * HP];
      br[k] = gBc[(size_t)(tw + k) * HN];
      wv[k] = Wp[tw + k];              // wave-uniform address
    }

    // ---- pack (fold decay weight into X) + transposed LDS write ----
    const int trow = wid * 8;
    #pragma unroll
    for (int k = 0; k < 8; ++k) {
      Xl[lane * 33 + trow + k] = pack_hilo(xr[k] * wv[k]);
      Bl[lane * 33 + trow + k] = pack_hilo(br[k]);
    }
    __syncthreads();

    // ---- fragment reads + extraction ----
    unsigned ca[2][8], cb[2][8];
    #pragma unroll
    for (int mt = 0; mt < 2; ++mt) {
      const int base = (m0 + mt * 16 + l15) * 33 + l4 * 8;
      #pragma unroll
      for (int j = 0; j < 8; ++j) ca[mt][j] = Xl[base + j];
    }
    #pragma unroll
    for (int nt = 0; nt < 2; ++nt) {
      const int base = (n0 + nt * 16 + l15) * 33 + l4 * 8;
      #pragma unroll
      for (int j = 0; j < 8; ++j) cb[nt][j] = Bl[base + j];
    }

    short8 ahi[2], alo[2], bhi[2], blo[2];
    #pragma unroll
    for (int mt = 0; mt < 2; ++mt) {
      ahi[mt] = mk_frag(__builtin_amdgcn_perm(ca[mt][1], ca[mt][0], 0x05040100),
                        __builtin_amdgcn_perm(ca[mt][3], ca[mt][2], 0x05040100),
                        __builtin_amdgcn_perm(ca[mt][5], ca[mt][4], 0x05040100),
                        __builtin_amdgcn_perm(ca[mt][7], ca[mt][6], 0x05040100));
      alo[mt] = mk_frag(__builtin_amdgcn_perm(ca[mt][1], ca[mt][0], 0x07060302),
                        __builtin_amdgcn_perm(ca[mt][3], ca[mt][2], 0x07060302),
                        __builtin_amdgcn_perm(ca[mt][5], ca[mt][4], 0x07060302),
                        __builtin_amdgcn_perm(ca[mt][7], ca[mt][6], 0x07060302));
    }
    #pragma unroll
    for (int nt = 0; nt < 2; ++nt) {
      bhi[nt] = mk_frag(__builtin_amdgcn_perm(cb[nt][1], cb[nt][0], 0x05040100),
                        __builtin_amdgcn_perm(cb[nt][3], cb[nt][2], 0x05040100),
                        __builtin_amdgcn_perm(cb[nt][5], cb[nt][4], 0x05040100),
                        __builtin_amdgcn_perm(cb[nt][7], cb[nt][6], 0x05040100));
      blo[nt] = mk_frag(__builtin_amdgcn_perm(cb[nt][1], cb[nt][0], 0x07060302),
                        __builtin_amdgcn_perm(cb[nt][3], cb[nt][2], 0x07060302),
                        __builtin_amdgcn_perm(cb[nt][5], cb[nt][4], 0x07060302),
                        __builtin_amdgcn_perm(cb[nt][7], cb[nt][6], 0x07060302));
    }

    // ---- 3-term bf16-split MFMA: hi*hi + hi*lo + lo*hi ----
    #pragma unroll
    for (int mt = 0; mt < 2; ++mt)
      #pragma unroll
      for (int nt = 0; nt < 2; ++nt) {
        f32x4 c = acc[mt][nt];
        c = __builtin_amdgcn_mfma_f32_16x16x32_bf16(alo[mt], bhi[nt], c, 0, 0, 0);
        c = __builtin_amdgcn_mfma_f32_16x16x32_bf16(ahi[mt], blo[nt], c, 0, 0, 0);
        c = __builtin_amdgcn_mfma_f32_16x16x32_bf16(ahi[mt], bhi[nt], c, 0, 0, 0);
        acc[mt][nt] = c;
      }
    __syncthreads();   // guard LDS reuse by next iteration
  }

  // ---- epilogue: C/D layout col=lane&15, row=(lane>>4)*4+r (m89-verified) ----
  float* outp = out + (size_t)pair * P * N;  // out[b,h,p,n]
  #pragma unroll
  for (int mt = 0; mt < 2; ++mt)
    #pragma unroll
    for (int nt = 0; nt < 2; ++nt) {
      const int p = m0 + mt * 16 + l4 * 4;
      const int n = n0 + nt * 16 + l15;
      #pragma unroll
      for (int r = 0; r < 4; ++r)
        atomicAdd(&outp[(size_t)(p + r) * N + n], acc[mt][nt][r]);
    }
}

extern "C" void kernel_launch(void* const* d_in, const int* in_sizes, int n_in,
                              void* d_out, int out_size, void* d_ws, size_t ws_size,
                              hipStream_t stream) {
  const float* X = (const float*)d_in[0];   // (b, s, h, p)
  const float* A = (const float*)d_in[1];   // (b, s, h)
  const float* B = (const float*)d_in[2];   // (b, s, h, n)
  float* out = (float*)d_out;               // (b, h, p, n)
  float* W   = (float*)d_ws;                // Bn*H*S floats = 2 MB scratch

  // out is poisoned 0xAA before every launch; atomics need zeros
  hipMemsetAsync(d_out, 0, (size_t)out_size * sizeof(float), stream);

  scan_weights<<<Bn * H, 256, 0, stream>>>(A, W);
  outer_accum<<<Bn * H * NCH, 256, 0, stream>>>(X, B, W, out);
}

// Round 7
// 295.353 us; speedup vs baseline: 2.1740x; 1.0026x over previous
//
#include <hip/hip_runtime.h>

// Shapes fixed by setup_inputs(): b=8, s=4096, h=16, p=64, n=64, L=64.
// Reduction: out[b,h,p,n] = sum_t exp(Total(b,h) - P(b,h,t)) * X[b,t,h,p] * B[b,t,h,n]
// = a 64x64 GEMM with K=t=4096 per (b,h) pair -> MFMA (bf16 3-term split).

constexpr int Bn = 8;
constexpr int S  = 4096;
constexpr int H  = 16;
constexpr int P  = 64;
constexpr int N  = 64;

constexpr int NCH = 8;         // t-chunks per (b,h) pair -> 1024 blocks
constexpr int TCH = S / NCH;   // 512 timesteps per chunk
constexpr int TB  = 32;        // timesteps per K-iteration (= MFMA K)
constexpr int NIT = TCH / TB;  // 16 iterations per block

typedef __attribute__((ext_vector_type(4))) float f32x4;
typedef __attribute__((ext_vector_type(8))) short short8;

// ---------------- Kernel 1: per-(b,h) prefix scan of A -> weights ----------------
__global__ __launch_bounds__(256) void scan_weights(
    const float* __restrict__ A, float* __restrict__ W) {
  const int pair = blockIdx.x;         // 0..Bn*H-1
  const int bb = pair / H, hh = pair % H;
  const int tid = threadIdx.x;
  constexpr int TPT = S / 256;         // 16 elements per thread

  float vals[TPT];
  float local = 0.f;
  const int t0 = tid * TPT;
  #pragma unroll
  for (int i = 0; i < TPT; ++i) {
    float a = A[((size_t)bb * S + t0 + i) * H + hh];
    local += a;
    vals[i] = local;                   // inclusive within thread
  }

  __shared__ float sums[256];
  sums[tid] = local;
  __syncthreads();
  for (int off = 1; off < 256; off <<= 1) {
    float v = sums[tid];
    float add = (tid >= off) ? sums[tid - off] : 0.f;
    __syncthreads();
    sums[tid] = v + add;
    __syncthreads();
  }
  const float total = sums[255];
  const float excl  = sums[tid] - local;

  float* Wp = W + (size_t)pair * S;
  #pragma unroll
  for (int i = 0; i < TPT; ++i) {
    Wp[t0 + i] = __expf(total - (excl + vals[i]));  // exponent <= 0 (A <= 0)
  }
}

// fp32 -> (hi bf16 in low half, lo bf16 in high half), truncation split.
// x ~= bf16(hi) + bf16(lo); dropped lo*lo term ~2^-16 relative.
__device__ __forceinline__ unsigned pack_hilo(float x) {
  unsigned bx = __float_as_uint(x);
  unsigned hi = bx >> 16;
  float rf = x - __uint_as_float(bx & 0xFFFF0000u);
  unsigned lo = __float_as_uint(rf) & 0xFFFF0000u;
  return hi | lo;
}

__device__ __forceinline__ short8 mk_frag(unsigned a0, unsigned a1,
                                          unsigned a2, unsigned a3) {
  union { unsigned u[4]; short8 s; } u;
  u.u[0] = a0; u.u[1] = a1; u.u[2] = a2; u.u[3] = a3;
  return u.s;
}

// ---------------- Kernel 2: MFMA outer-product accumulation ----------------
// One block per (pair, chunk). 256 threads = 4 waves; wave w owns the 32x32
// output quadrant (m0=(w&1)*32, n0=(w>>1)*32) as 4 MFMA 16x16 tiles.
// Software-pipelined (round-6 lesson: single-buffered version was latency-bound
// at 111 us with all pipes <18% busy): iter k+1's 16 coalesced global dword
// loads are issued BEFORE computing iter k from LDS; the pack+LDS-store (which
// waits on vmcnt) runs AFTER the MFMAs, so HBM latency hides under compute.
// Double-buffered LDS (34 KB), one barrier per iteration.
// LDS layout: [col][t] packed hi|lo bf16, row stride 33 u32 (2-way banks, free).
#define LOADREG(tt0)                                                      \
  do {                                                                    \
    const int tw_ = (tt0) + wid * 8;   /* this wave stages 8 t-rows */    \
    w0 = *(const float4*)(Wp + tw_);                                      \
    w1 = *(const float4*)(Wp + tw_ + 4);                                  \
    xr[0] = gXc[(size_t)(tw_ + 0) * HP]; br[0] = gBc[(size_t)(tw_ + 0) * HN]; \
    xr[1] = gXc[(size_t)(tw_ + 1) * HP]; br[1] = gBc[(size_t)(tw_ + 1) * HN]; \
    xr[2] = gXc[(size_t)(tw_ + 2) * HP]; br[2] = gBc[(size_t)(tw_ + 2) * HN]; \
    xr[3] = gXc[(size_t)(tw_ + 3) * HP]; br[3] = gBc[(size_t)(tw_ + 3) * HN]; \
    xr[4] = gXc[(size_t)(tw_ + 4) * HP]; br[4] = gBc[(size_t)(tw_ + 4) * HN]; \
    xr[5] = gXc[(size_t)(tw_ + 5) * HP]; br[5] = gBc[(size_t)(tw_ + 5) * HN]; \
    xr[6] = gXc[(size_t)(tw_ + 6) * HP]; br[6] = gBc[(size_t)(tw_ + 6) * HN]; \
    xr[7] = gXc[(size_t)(tw_ + 7) * HP]; br[7] = gBc[(size_t)(tw_ + 7) * HN]; \
  } while (0)

#define PACKSTORE(buf)                                                    \
  do {                                                                    \
    unsigned* Xd_ = &Xl[buf][lane * 33 + wid * 8];                        \
    unsigned* Bd_ = &Bl[buf][lane * 33 + wid * 8];                        \
    Xd_[0] = pack_hilo(xr[0] * w0.x);  Bd_[0] = pack_hilo(br[0]);         \
    Xd_[1] = pack_hilo(xr[1] * w0.y);  Bd_[1] = pack_hilo(br[1]);         \
    Xd_[2] = pack_hilo(xr[2] * w0.z);  Bd_[2] = pack_hilo(br[2]);         \
    Xd_[3] = pack_hilo(xr[3] * w0.w);  Bd_[3] = pack_hilo(br[3]);         \
    Xd_[4] = pack_hilo(xr[4] * w1.x);  Bd_[4] = pack_hilo(br[4]);         \
    Xd_[5] = pack_hilo(xr[5] * w1.y);  Bd_[5] = pack_hilo(br[5]);         \
    Xd_[6] = pack_hilo(xr[6] * w1.z);  Bd_[6] = pack_hilo(br[6]);         \
    Xd_[7] = pack_hilo(xr[7] * w1.w);  Bd_[7] = pack_hilo(br[7]);         \
  } while (0)

__global__ __launch_bounds__(256) void outer_accum(
    const float* __restrict__ X, const float* __restrict__ Bm,
    const float* __restrict__ W, float* __restrict__ out) {
  __shared__ unsigned Xl[2][64 * 33];  // [col p][t] hi|lo packed, stride 33 u32
  __shared__ unsigned Bl[2][64 * 33];  // [col n][t]

  const int bid  = blockIdx.x;
  const int pair = bid / NCH;
  const int ch   = bid % NCH;
  const int tid  = threadIdx.x;
  const int lane = tid & 63;
  const int wid  = __builtin_amdgcn_readfirstlane(tid >> 6);  // 0..3, SGPR
  const int t_begin = ch * TCH;

  const int bb = pair / H, hh = pair % H;
  constexpr int HP = H * P;            // 1024 floats: X row stride over t
  constexpr int HN = H * N;            // 1024 floats: B row stride over t

  // staging: lane = column index (p for X, n for B); coalesced dword loads
  const float* gXc = X  + (size_t)bb * S * HP + (size_t)hh * P + lane;
  const float* gBc = Bm + (size_t)bb * S * HN + (size_t)hh * N + lane;
  const float* Wp  = W + (size_t)pair * S;

  // compute mapping: wave quadrant + MFMA lane roles
  const int m0 = (wid & 1) * 32;
  const int n0 = (wid >> 1) * 32;
  const int l15 = lane & 15;
  const int l4  = lane >> 4;           // k-group (k = l4*8 + j), C row-group

  f32x4 acc[2][2];
  #pragma unroll
  for (int mt = 0; mt < 2; ++mt)
    #pragma unroll
    for (int nt = 0; nt < 2; ++nt) acc[mt][nt] = (f32x4)0.f;

  float xr[8], br[8];
  float4 w0, w1;

  LOADREG(t_begin);
  PACKSTORE(0);
  __syncthreads();                     // buf0 ready

  for (int it = 0; it < NIT; ++it) {
    const int cur = it & 1;
    if (it + 1 < NIT) LOADREG(t_begin + (it + 1) * TB);  // prefetch (in flight)

    // ---- fragment reads + extraction from current buffer ----
    const unsigned* Xc = &Xl[cur][0];
    const unsigned* Bc = &Bl[cur][0];
    unsigned ca[2][8], cb[2][8];
    #pragma unroll
    for (int mt = 0; mt < 2; ++mt) {
      const int base = (m0 + mt * 16 + l15) * 33 + l4 * 8;
      #pragma unroll
      for (int j = 0; j < 8; ++j) ca[mt][j] = Xc[base + j];
    }
    #pragma unroll
    for (int nt = 0; nt < 2; ++nt) {
      const int base = (n0 + nt * 16 + l15) * 33 + l4 * 8;
      #pragma unroll
      for (int j = 0; j < 8; ++j) cb[nt][j] = Bc[base + j];
    }

    short8 ahi[2], alo[2], bhi[2], blo[2];
    #pragma unroll
    for (int mt = 0; mt < 2; ++mt) {
      ahi[mt] = mk_frag(__builtin_amdgcn_perm(ca[mt][1], ca[mt][0], 0x05040100),
                        __builtin_amdgcn_perm(ca[mt][3], ca[mt][2], 0x05040100),
                        __builtin_amdgcn_perm(ca[mt][5], ca[mt][4], 0x05040100),
                        __builtin_amdgcn_perm(ca[mt][7], ca[mt][6], 0x05040100));
      alo[mt] = mk_frag(__builtin_amdgcn_perm(ca[mt][1], ca[mt][0], 0x07060302),
                        __builtin_amdgcn_perm(ca[mt][3], ca[mt][2], 0x07060302),
                        __builtin_amdgcn_perm(ca[mt][5], ca[mt][4], 0x07060302),
                        __builtin_amdgcn_perm(ca[mt][7], ca[mt][6], 0x07060302));
    }
    #pragma unroll
    for (int nt = 0; nt < 2; ++nt) {
      bhi[nt] = mk_frag(__builtin_amdgcn_perm(cb[nt][1], cb[nt][0], 0x05040100),
                        __builtin_amdgcn_perm(cb[nt][3], cb[nt][2], 0x05040100),
                        __builtin_amdgcn_perm(cb[nt][5], cb[nt][4], 0x05040100),
                        __builtin_amdgcn_perm(cb[nt][7], cb[nt][6], 0x05040100));
      blo[nt] = mk_frag(__builtin_amdgcn_perm(cb[nt][1], cb[nt][0], 0x07060302),
                        __builtin_amdgcn_perm(cb[nt][3], cb[nt][2], 0x07060302),
                        __builtin_amdgcn_perm(cb[nt][5], cb[nt][4], 0x07060302),
                        __builtin_amdgcn_perm(cb[nt][7], cb[nt][6], 0x07060302));
    }

    // ---- 3-term bf16-split MFMA: hi*hi + hi*lo + lo*hi ----
    #pragma unroll
    for (int mt = 0; mt < 2; ++mt)
      #pragma unroll
      for (int nt = 0; nt < 2; ++nt) {
        f32x4 c = acc[mt][nt];
        c = __builtin_amdgcn_mfma_f32_16x16x32_bf16(alo[mt], bhi[nt], c, 0, 0, 0);
        c = __builtin_amdgcn_mfma_f32_16x16x32_bf16(ahi[mt], blo[nt], c, 0, 0, 0);
        c = __builtin_amdgcn_mfma_f32_16x16x32_bf16(ahi[mt], bhi[nt], c, 0, 0, 0);
        acc[mt][nt] = c;
      }

    // ---- write prefetched tile into the other buffer (waits vmcnt here) ----
    if (it + 1 < NIT) PACKSTORE(cur ^ 1);
    __syncthreads();   // one barrier per iteration
  }

  // ---- epilogue: C/D layout col=lane&15, row=(lane>>4)*4+r (m89-verified) ----
  float* outp = out + (size_t)pair * P * N;  // out[b,h,p,n]
  #pragma unroll
  for (int mt = 0; mt < 2; ++mt)
    #pragma unroll
    for (int nt = 0; nt < 2; ++nt) {
      const int p = m0 + mt * 16 + l4 * 4;
      const int n = n0 + nt * 16 + l15;
      #pragma unroll
      for (int r = 0; r < 4; ++r)
        atomicAdd(&outp[(size_t)(p + r) * N + n], acc[mt][nt][r]);
    }
}

extern "C" void kernel_launch(void* const* d_in, const int* in_sizes, int n_in,
                              void* d_out, int out_size, void* d_ws, size_t ws_size,
                              hipStream_t stream) {
  const float* X = (const float*)d_in[0];   // (b, s, h, p)
  const float* A = (const float*)d_in[1];   // (b, s, h)
  const float* B = (const float*)d_in[2];   // (b, s, h, n)
  float* out = (float*)d_out;               // (b, h, p, n)
  float* W   = (float*)d_ws;                // Bn*H*S floats = 2 MB scratch

  // out is poisoned 0xAA before every launch; atomics need zeros
  hipMemsetAsync(d_out, 0, (size_t)out_size * sizeof(float), stream);

  scan_weights<<<Bn * H, 256, 0, stream>>>(A, W);
  outer_accum<<<Bn * H * NCH, 256, 0, stream>>>(X, B, W, out);
}